// Round 12
// baseline (146.788 us; speedup 1.0000x reference)
//
#include <hip/hip_runtime.h>
#include <math.h>

#define NROW 4096
#define FDIM 512
#define MARGIN 1.0f

typedef __attribute__((ext_vector_type(8))) short short8;
typedef __attribute__((ext_vector_type(4))) float floatx4;

__device__ inline unsigned short f2bf(float x) {
    unsigned u = __float_as_uint(x);
    return (unsigned short)((u + 0x7FFFu + ((u >> 16) & 1u)) >> 16);
}
__device__ inline float h2f(unsigned short u) {
    _Float16 h; __builtin_memcpy(&h, &u, 2); return (float)h;
}
__device__ inline unsigned short f2h(float f) {
    _Float16 h = (_Float16)f; unsigned short u; __builtin_memcpy(&u, &h, 2); return u;
}
__device__ inline void glds16(const unsigned short* g, unsigned short* l) {
    __builtin_amdgcn_global_load_lds(
        (const __attribute__((address_space(1))) unsigned int*)g,
        (__attribute__((address_space(3))) unsigned int*)l, 16, 0, 0);
}

// ---------------------------------------------------------------------------
// Fused prep: bf16 convert + row norms + zero rns/loss/done. One wave per row.
// ---------------------------------------------------------------------------
__global__ __launch_bounds__(64) void prep_kernel(
    const float* __restrict__ a, const float* __restrict__ b,
    unsigned short* __restrict__ abf, unsigned short* __restrict__ bbf,
    float* __restrict__ na, float* __restrict__ nb,
    float* __restrict__ rns, float* __restrict__ loss,
    unsigned int* __restrict__ done) {
    int row  = blockIdx.x;
    int lane = threadIdx.x;
    const float4* a4 = (const float4*)(a + (size_t)row * FDIM);
    const float4* b4 = (const float4*)(b + (size_t)row * FDIM);
    ushort4* au = (ushort4*)(abf + (size_t)row * FDIM);
    ushort4* bu = (ushort4*)(bbf + (size_t)row * FDIM);
    float sa = 0.f, sb = 0.f;
    #pragma unroll
    for (int f = lane; f < FDIM / 4; f += 64) {
        float4 va = a4[f];
        float4 vb = b4[f];
        sa += va.x * va.x + va.y * va.y + va.z * va.z + va.w * va.w;
        sb += vb.x * vb.x + vb.y * vb.y + vb.z * vb.z + vb.w * vb.w;
        ushort4 ua = { f2bf(va.x), f2bf(va.y), f2bf(va.z), f2bf(va.w) };
        ushort4 ub = { f2bf(vb.x), f2bf(vb.y), f2bf(vb.z), f2bf(vb.w) };
        au[f] = ua;
        bu[f] = ub;
    }
    #pragma unroll
    for (int o = 32; o > 0; o >>= 1) {
        sa += __shfl_down(sa, o);
        sb += __shfl_down(sb, o);
    }
    if (lane == 0) {
        na[row] = sa;
        nb[row] = sb;
        rns[row] = 0.f;
        if (row == 0) { loss[0] = 0.f; done[0] = 0u; }
    }
}

// ---------------------------------------------------------------------------
// MFMA pass: 128x128 tile of S = b @ a^T, BK=32 double-buffered, 4 waves 2x2.
// D stored in C-FRAGMENT ORDER (coalesced 16B stores, no LDS transpose).
// MODE 0: phase1 (negsum) + store D fragments
// MODE 1: phase1 only                   (fallback when ws too small)
// MODE 2: phase2 recompute + hinge^2    (fallback)
// ---------------------------------------------------------------------------
template <int MODE>
__global__ __launch_bounds__(256) void pass_mfma(
    const unsigned short* __restrict__ abf, const unsigned short* __restrict__ bbf,
    const int* __restrict__ labels,
    const float* __restrict__ na, const float* __restrict__ nb,
    float* __restrict__ rns, unsigned short* __restrict__ Dws,
    float* __restrict__ loss_sum)
{
    // 32 KB: 2 x (As 8KB + Bs 8KB) double buffer
    __shared__ __align__(16) unsigned short arena[16384];
    __shared__ int   li_s[128], lj_s[128];
    __shared__ float nb_s[128], na_s[128], rbi_s[128], rbj_s[128];

    const int t    = threadIdx.x;
    const int lane = t & 63;
    const int w    = t >> 6;
    const int wi   = w >> 1, wj = w & 1;
    // supertile swizzle: 8x8 blocks per supertile for XCD/L2 locality
    const int bid  = blockIdx.x;
    const int sup  = bid >> 6, loc = bid & 63;
    const int by   = ((sup >> 2) << 3) | (loc >> 3);
    const int bx   = ((sup & 3) << 3) | (loc & 7);
    const int ti   = by * 128;           // b-row (i) origin
    const int tj   = bx * 128;           // a-row (j) origin
    const int lr   = lane & 15;
    const int lq   = lane >> 4;

    floatx4 acc[4][4];
    #pragma unroll
    for (int i = 0; i < 4; ++i)
        #pragma unroll
        for (int j = 0; j < 4; ++j)
            acc[i][j] = (floatx4){0.f, 0.f, 0.f, 0.f};

    if (t < 128) {
        li_s[t] = labels[ti + t];
        nb_s[t] = nb[ti + t];
        if (MODE == 2) rbi_s[t] = rns[ti + t];
    } else {
        int u = t - 128;
        lj_s[u] = labels[tj + u];
        na_s[u] = na[tj + u];
        if (MODE == 2) rbj_s[u] = rns[tj + u];
    }

    // stage one BK=32 tile pair into buffer `buf`
    auto stage = [&](int kk, int buf) {
        unsigned short* As = arena + buf * 8192;
        unsigned short* Bs = arena + 4096 + buf * 8192;
        #pragma unroll
        for (int l = 0; l < 2; ++l) {
            int c   = t + l * 256;       // 0..511: 16B chunk id
            int row = c >> 2;
            int q   = c & 3;
            glds16(abf + (size_t)(tj + row) * FDIM + kk + q * 8, As + c * 8);
            glds16(bbf + (size_t)(ti + row) * FDIM + kk + q * 8, Bs + c * 8);
        }
    };

    stage(0, 0);
    __syncthreads();

    #pragma unroll
    for (int it = 0; it < FDIM / 32; ++it) {
        if (it < FDIM / 32 - 1) stage((it + 1) * 32, (it + 1) & 1);

        const unsigned short* As = arena + (it & 1) * 8192;
        const unsigned short* Bs = As + 4096;
        short8 af[4], bf[4];
        #pragma unroll
        for (int ri = 0; ri < 4; ++ri)
            af[ri] = *(const short8*)&Bs[(wi * 64 + ri * 16 + lr) * 32 + lq * 8];
        #pragma unroll
        for (int rj = 0; rj < 4; ++rj)
            bf[rj] = *(const short8*)&As[(wj * 64 + rj * 16 + lr) * 32 + lq * 8];
        #pragma unroll
        for (int ri = 0; ri < 4; ++ri)
            #pragma unroll
            for (int rj = 0; rj < 4; ++rj)
                acc[ri][rj] = __builtin_amdgcn_mfma_f32_16x16x32_bf16(
                    af[ri], bf[rj], acc[ri][rj], 0, 0, 0);
        __syncthreads();
    }

    if (MODE == 0 || MODE == 1) {
        // phase-1 epilogue: C/D layout col = lane&15, row = quad*4 + reg
        unsigned short* dblk = Dws + (size_t)bid * 16384;
        #pragma unroll
        for (int ri = 0; ri < 4; ++ri) {
            float rs[4] = {0.f, 0.f, 0.f, 0.f};
            unsigned short dloc[16];
            #pragma unroll
            for (int rj = 0; rj < 4; ++rj) {
                int   jl  = wj * 64 + rj * 16 + lr;
                float naj = na_s[jl];
                int   ljv = lj_s[jl];
                #pragma unroll
                for (int r = 0; r < 4; ++r) {
                    int   il  = wi * 64 + ri * 16 + lq * 4 + r;
                    float dsq = nb_s[il] + naj - 2.f * acc[ri][rj][r];
                    float D   = sqrtf(fmaxf(dsq, 0.f));
                    if (li_s[il] != ljv) rs[r] += __expf(MARGIN - D);
                    if (MODE == 0) dloc[rj * 4 + r] = f2h(D);
                }
            }
            #pragma unroll
            for (int r = 0; r < 4; ++r) {
                #pragma unroll
                for (int o = 8; o > 0; o >>= 1) rs[r] += __shfl_down(rs[r], o, 16);
            }
            if (lr == 0) {
                #pragma unroll
                for (int r = 0; r < 4; ++r)
                    atomicAdd(&rns[ti + wi * 64 + ri * 16 + lq * 4 + r], rs[r]);
            }
            if (MODE == 0) {
                // fragment-order store, coalesced 16B per lane
                *(short8*)&dblk[(ri * 2 + 0) * 2048 + t * 8] = *(short8*)&dloc[0];
                *(short8*)&dblk[(ri * 2 + 1) * 2048 + t * 8] = *(short8*)&dloc[8];
            }
        }
    } else {
        // phase-2 recompute epilogue
        float local = 0.f;
        #pragma unroll
        for (int ri = 0; ri < 4; ++ri)
            #pragma unroll
            for (int rj = 0; rj < 4; ++rj) {
                int jl  = wj * 64 + rj * 16 + lr;
                int ljv = lj_s[jl];
                float naj = na_s[jl], rbj = rbj_s[jl];
                #pragma unroll
                for (int r = 0; r < 4; ++r) {
                    int il = wi * 64 + ri * 16 + lq * 4 + r;
                    int i  = ti + il, j = tj + jl;
                    if (li_s[il] == ljv && i != j) {
                        float dsq = nb_s[il] + naj - 2.f * acc[ri][rj][r];
                        float D   = sqrtf(fmaxf(dsq, 0.f));
                        float J   = __logf(rbi_s[il] + rbj) + D;
                        float h   = fmaxf(J, 0.f);
                        local += h * h;
                    }
                }
            }
        #pragma unroll
        for (int o = 32; o > 0; o >>= 1) local += __shfl_down(local, o);
        __shared__ float part[4];
        if (lane == 0) part[w] = local;
        __syncthreads();
        if (t == 0) atomicAdd(loss_sum, part[0] + part[1] + part[2] + part[3]);
    }
}

// ---------------------------------------------------------------------------
// Phase-2 sweep + fused finalize: one block per GEMM tile; reads D fragments
// back in C-fragment order (coalesced 16B). The LAST block to finish (device
// atomic done-counter) computes out = loss / (2*num_pos).
// ---------------------------------------------------------------------------
__global__ __launch_bounds__(256) void pass2_sweep(
    const unsigned short* __restrict__ Dws, const int* __restrict__ labels,
    const float* __restrict__ rns, float* __restrict__ loss_sum,
    unsigned int* __restrict__ done, float* __restrict__ out,
    unsigned int nblocks)
{
    __shared__ int   lab_i[128], lab_j[128];
    __shared__ float rb_i[128], rb_j[128];

    const int t    = threadIdx.x;
    const int lane = t & 63;
    const int w    = t >> 6;
    const int wi   = w >> 1, wj = w & 1;
    const int bid  = blockIdx.x;
    const int sup  = bid >> 6, loc = bid & 63;
    const int by   = ((sup >> 2) << 3) | (loc >> 3);
    const int bx   = ((sup & 3) << 3) | (loc & 7);
    const int ti   = by * 128;
    const int tj   = bx * 128;
    const int lr   = lane & 15;
    const int lq   = lane >> 4;

    if (t < 128) {
        lab_i[t] = labels[ti + t];
        rb_i[t]  = rns[ti + t];
    } else {
        int u = t - 128;
        lab_j[u] = labels[tj + u];
        rb_j[u]  = rns[tj + u];
    }
    __syncthreads();

    const unsigned short* dblk = Dws + (size_t)bid * 16384;
    float local = 0.f;
    #pragma unroll
    for (int ri = 0; ri < 4; ++ri) {
        short8 d0 = *(const short8*)&dblk[(ri * 2 + 0) * 2048 + t * 8];
        short8 d1 = *(const short8*)&dblk[(ri * 2 + 1) * 2048 + t * 8];
        #pragma unroll
        for (int rj = 0; rj < 4; ++rj) {
            int jl  = wj * 64 + rj * 16 + lr;
            int ljv = lab_j[jl];
            #pragma unroll
            for (int r = 0; r < 4; ++r) {
                int il = wi * 64 + ri * 16 + lq * 4 + r;
                if (lab_i[il] == ljv && (ti + il) != (tj + jl)) {
                    unsigned short du = (rj < 2)
                        ? (unsigned short)d0[rj * 4 + r]
                        : (unsigned short)d1[(rj - 2) * 4 + r];
                    float J = __logf(rb_i[il] + rb_j[jl]) + h2f(du);
                    float h = fmaxf(J, 0.f);
                    local += h * h;
                }
            }
        }
    }
    #pragma unroll
    for (int o = 32; o > 0; o >>= 1) local += __shfl_down(local, o);
    __shared__ float part[4];
    if (lane == 0) part[w] = local;
    __syncthreads();

    __shared__ bool last;
    if (t == 0) {
        atomicAdd(loss_sum, part[0] + part[1] + part[2] + part[3]);
        __threadfence();                         // release loss before counter
        unsigned int prev = atomicAdd(done, 1u);
        last = (prev == nblocks - 1);
    }
    __syncthreads();

    if (last) {
        // final block: histogram labels -> num_pos, write the scalar output
        __shared__ int hist[16];
        if (t < 16) hist[t] = 0;
        __syncthreads();
        for (int i = t; i < NROW; i += 256) atomicAdd(&hist[labels[i] & 15], 1);
        __syncthreads();
        if (t == 0) {
            __threadfence();                     // acquire all loss adds
            long long np = 0;
            for (int c = 0; c < 16; ++c)
                np += (long long)hist[c] * (long long)(hist[c] - 1);
            out[0] = __hip_atomic_load(loss_sum, __ATOMIC_RELAXED,
                                       __HIP_MEMORY_SCOPE_AGENT)
                     / (2.0f * (float)np);
        }
    }
}

// ---------------------------------------------------------------------------
// Fallback finalize (only used on the MODE 1/2 path)
// ---------------------------------------------------------------------------
__global__ __launch_bounds__(256) void finalize_kernel(const int* __restrict__ labels,
                                                       const float* __restrict__ loss_sum,
                                                       float* __restrict__ out) {
    __shared__ int hist[16];
    int t = threadIdx.x;
    if (t < 16) hist[t] = 0;
    __syncthreads();
    for (int i = t; i < NROW; i += 256) atomicAdd(&hist[labels[i] & 15], 1);
    __syncthreads();
    if (t == 0) {
        long long np = 0;
        for (int c = 0; c < 16; ++c) np += (long long)hist[c] * (long long)(hist[c] - 1);
        out[0] = loss_sum[0] / (2.0f * (float)np);
    }
}

// ---------------------------------------------------------------------------
extern "C" void kernel_launch(void* const* d_in, const int* in_sizes, int n_in,
                              void* d_out, int out_size, void* d_ws, size_t ws_size,
                              hipStream_t stream) {
    const float* a      = (const float*)d_in[0];
    const float* b      = (const float*)d_in[1];
    const int*   labels = (const int*)d_in[2];
    float* out = (float*)d_out;

    // ws: abf(8MB) | bbf(8MB) | na,nb,rns,loss,done(+pad) | Dws(32MB fp16)
    unsigned short* abf = (unsigned short*)d_ws;
    unsigned short* bbf = abf + (size_t)NROW * FDIM;
    float* fws  = (float*)(bbf + (size_t)NROW * FDIM);
    float* na   = fws;
    float* nb   = fws + NROW;
    float* rns  = fws + 2 * NROW;
    float* loss = fws + 3 * NROW;
    unsigned int* done = (unsigned int*)(fws + 3 * NROW + 1);
    unsigned short* Dws = (unsigned short*)(fws + 3 * NROW + 4);   // 16B aligned

    size_t need = ((char*)Dws - (char*)d_ws) + (size_t)NROW * NROW * 2;

    prep_kernel<<<NROW, 64, 0, stream>>>(a, b, abf, bbf, na, nb, rns, loss, done);

    dim3 grid((NROW / 128) * (NROW / 128));   // 1024 blocks
    if (ws_size >= need) {
        pass_mfma<0><<<grid, 256, 0, stream>>>(abf, bbf, labels, na, nb, rns, Dws, loss);
        pass2_sweep<<<grid, 256, 0, stream>>>(Dws, labels, rns, loss, done, out,
                                              grid.x);
    } else {
        pass_mfma<1><<<grid, 256, 0, stream>>>(abf, bbf, labels, na, nb, rns, Dws, loss);
        pass_mfma<2><<<grid, 256, 0, stream>>>(abf, bbf, labels, na, nb, rns, Dws, loss);
        finalize_kernel<<<1, 256, 0, stream>>>(labels, loss, out);
    }
}

// Round 13
// 134.788 us; speedup vs baseline: 1.0890x; 1.0890x over previous
//
#include <hip/hip_runtime.h>
#include <math.h>

#define NROW 4096
#define FDIM 512
#define MARGIN 1.0f

typedef __attribute__((ext_vector_type(8))) short short8;
typedef __attribute__((ext_vector_type(4))) float floatx4;

__device__ inline unsigned short f2bf(float x) {
    unsigned u = __float_as_uint(x);
    return (unsigned short)((u + 0x7FFFu + ((u >> 16) & 1u)) >> 16);
}
__device__ inline float h2f(unsigned short u) {
    _Float16 h; __builtin_memcpy(&h, &u, 2); return (float)h;
}
__device__ inline unsigned short f2h(float f) {
    _Float16 h = (_Float16)f; unsigned short u; __builtin_memcpy(&u, &h, 2); return u;
}
__device__ inline void glds16(const unsigned short* g, unsigned short* l) {
    __builtin_amdgcn_global_load_lds(
        (const __attribute__((address_space(1))) unsigned int*)g,
        (__attribute__((address_space(3))) unsigned int*)l, 16, 0, 0);
}

// ---------------------------------------------------------------------------
// Fused prep: bf16 convert + row norms + zero rns/loss. One wave per row.
// ---------------------------------------------------------------------------
__global__ __launch_bounds__(64) void prep_kernel(
    const float* __restrict__ a, const float* __restrict__ b,
    unsigned short* __restrict__ abf, unsigned short* __restrict__ bbf,
    float* __restrict__ na, float* __restrict__ nb,
    float* __restrict__ rns, float* __restrict__ loss) {
    int row  = blockIdx.x;
    int lane = threadIdx.x;
    const float4* a4 = (const float4*)(a + (size_t)row * FDIM);
    const float4* b4 = (const float4*)(b + (size_t)row * FDIM);
    ushort4* au = (ushort4*)(abf + (size_t)row * FDIM);
    ushort4* bu = (ushort4*)(bbf + (size_t)row * FDIM);
    float sa = 0.f, sb = 0.f;
    #pragma unroll
    for (int f = lane; f < FDIM / 4; f += 64) {
        float4 va = a4[f];
        float4 vb = b4[f];
        sa += va.x * va.x + va.y * va.y + va.z * va.z + va.w * va.w;
        sb += vb.x * vb.x + vb.y * vb.y + vb.z * vb.z + vb.w * vb.w;
        ushort4 ua = { f2bf(va.x), f2bf(va.y), f2bf(va.z), f2bf(va.w) };
        ushort4 ub = { f2bf(vb.x), f2bf(vb.y), f2bf(vb.z), f2bf(vb.w) };
        au[f] = ua;
        bu[f] = ub;
    }
    #pragma unroll
    for (int o = 32; o > 0; o >>= 1) {
        sa += __shfl_down(sa, o);
        sb += __shfl_down(sb, o);
    }
    if (lane == 0) {
        na[row] = sa;
        nb[row] = sb;
        rns[row] = 0.f;
        if (row == 0) loss[0] = 0.f;
    }
}

// ---------------------------------------------------------------------------
// MFMA pass: 128x128 tile of S = b @ a^T, BK=32 double-buffered, 4 waves 2x2.
// D is stored in C-FRAGMENT ORDER (no LDS transpose, no bank conflicts):
//   Dws[bid*16384 + h*2048 + t*8], h = ri*2 + (rj>=2), element = rj'*4 + r.
// Per store instruction lanes write consecutive 16B -> fully coalesced.
// MODE 0: phase1 (negsum) + store D fragments
// MODE 1: phase1 only                   (fallback when ws too small)
// MODE 2: phase2 recompute + hinge^2    (fallback)
// ---------------------------------------------------------------------------
template <int MODE>
__global__ __launch_bounds__(256) void pass_mfma(
    const unsigned short* __restrict__ abf, const unsigned short* __restrict__ bbf,
    const int* __restrict__ labels,
    const float* __restrict__ na, const float* __restrict__ nb,
    float* __restrict__ rns, unsigned short* __restrict__ Dws,
    float* __restrict__ loss_sum)
{
    // 32 KB: 2 x (As 8KB + Bs 8KB) double buffer
    __shared__ __align__(16) unsigned short arena[16384];
    __shared__ int   li_s[128], lj_s[128];
    __shared__ float nb_s[128], na_s[128], rbi_s[128], rbj_s[128];

    const int t    = threadIdx.x;
    const int lane = t & 63;
    const int w    = t >> 6;
    const int wi   = w >> 1, wj = w & 1;
    // supertile swizzle: 8x8 blocks per supertile for XCD/L2 locality
    const int bid  = blockIdx.x;
    const int sup  = bid >> 6, loc = bid & 63;
    const int by   = ((sup >> 2) << 3) | (loc >> 3);
    const int bx   = ((sup & 3) << 3) | (loc & 7);
    const int ti   = by * 128;           // b-row (i) origin
    const int tj   = bx * 128;           // a-row (j) origin
    const int lr   = lane & 15;
    const int lq   = lane >> 4;

    floatx4 acc[4][4];
    #pragma unroll
    for (int i = 0; i < 4; ++i)
        #pragma unroll
        for (int j = 0; j < 4; ++j)
            acc[i][j] = (floatx4){0.f, 0.f, 0.f, 0.f};

    if (t < 128) {
        li_s[t] = labels[ti + t];
        nb_s[t] = nb[ti + t];
        if (MODE == 2) rbi_s[t] = rns[ti + t];
    } else {
        int u = t - 128;
        lj_s[u] = labels[tj + u];
        na_s[u] = na[tj + u];
        if (MODE == 2) rbj_s[u] = rns[tj + u];
    }

    // stage one BK=32 tile pair into buffer `buf`
    auto stage = [&](int kk, int buf) {
        unsigned short* As = arena + buf * 8192;
        unsigned short* Bs = arena + 4096 + buf * 8192;
        #pragma unroll
        for (int l = 0; l < 2; ++l) {
            int c   = t + l * 256;       // 0..511: 16B chunk id
            int row = c >> 2;
            int q   = c & 3;
            glds16(abf + (size_t)(tj + row) * FDIM + kk + q * 8, As + c * 8);
            glds16(bbf + (size_t)(ti + row) * FDIM + kk + q * 8, Bs + c * 8);
        }
    };

    stage(0, 0);
    __syncthreads();

    #pragma unroll
    for (int it = 0; it < FDIM / 32; ++it) {
        if (it < FDIM / 32 - 1) stage((it + 1) * 32, (it + 1) & 1);

        const unsigned short* As = arena + (it & 1) * 8192;
        const unsigned short* Bs = As + 4096;
        short8 af[4], bf[4];
        #pragma unroll
        for (int ri = 0; ri < 4; ++ri)
            af[ri] = *(const short8*)&Bs[(wi * 64 + ri * 16 + lr) * 32 + lq * 8];
        #pragma unroll
        for (int rj = 0; rj < 4; ++rj)
            bf[rj] = *(const short8*)&As[(wj * 64 + rj * 16 + lr) * 32 + lq * 8];
        #pragma unroll
        for (int ri = 0; ri < 4; ++ri)
            #pragma unroll
            for (int rj = 0; rj < 4; ++rj)
                acc[ri][rj] = __builtin_amdgcn_mfma_f32_16x16x32_bf16(
                    af[ri], bf[rj], acc[ri][rj], 0, 0, 0);
        __syncthreads();
    }

    if (MODE == 0 || MODE == 1) {
        // phase-1 epilogue: C/D layout col = lane&15, row = quad*4 + reg
        unsigned short* dblk = Dws + (size_t)bid * 16384;
        #pragma unroll
        for (int ri = 0; ri < 4; ++ri) {
            float rs[4] = {0.f, 0.f, 0.f, 0.f};
            unsigned short dloc[16];
            #pragma unroll
            for (int rj = 0; rj < 4; ++rj) {
                int   jl  = wj * 64 + rj * 16 + lr;
                float naj = na_s[jl];
                int   ljv = lj_s[jl];
                #pragma unroll
                for (int r = 0; r < 4; ++r) {
                    int   il  = wi * 64 + ri * 16 + lq * 4 + r;
                    float dsq = nb_s[il] + naj - 2.f * acc[ri][rj][r];
                    float D   = sqrtf(fmaxf(dsq, 0.f));
                    if (li_s[il] != ljv) rs[r] += __expf(MARGIN - D);
                    if (MODE == 0) dloc[rj * 4 + r] = f2h(D);
                }
            }
            #pragma unroll
            for (int r = 0; r < 4; ++r) {
                #pragma unroll
                for (int o = 8; o > 0; o >>= 1) rs[r] += __shfl_down(rs[r], o, 16);
            }
            if (lr == 0) {
                #pragma unroll
                for (int r = 0; r < 4; ++r)
                    atomicAdd(&rns[ti + wi * 64 + ri * 16 + lq * 4 + r], rs[r]);
            }
            if (MODE == 0) {
                // fragment-order store, coalesced 16B per lane
                *(short8*)&dblk[(ri * 2 + 0) * 2048 + t * 8] = *(short8*)&dloc[0];
                *(short8*)&dblk[(ri * 2 + 1) * 2048 + t * 8] = *(short8*)&dloc[8];
            }
        }
    } else {
        // phase-2 recompute epilogue
        float local = 0.f;
        #pragma unroll
        for (int ri = 0; ri < 4; ++ri)
            #pragma unroll
            for (int rj = 0; rj < 4; ++rj) {
                int jl  = wj * 64 + rj * 16 + lr;
                int ljv = lj_s[jl];
                float naj = na_s[jl], rbj = rbj_s[jl];
                #pragma unroll
                for (int r = 0; r < 4; ++r) {
                    int il = wi * 64 + ri * 16 + lq * 4 + r;
                    int i  = ti + il, j = tj + jl;
                    if (li_s[il] == ljv && i != j) {
                        float dsq = nb_s[il] + naj - 2.f * acc[ri][rj][r];
                        float D   = sqrtf(fmaxf(dsq, 0.f));
                        float J   = __logf(rbi_s[il] + rbj) + D;
                        float h   = fmaxf(J, 0.f);
                        local += h * h;
                    }
                }
            }
        #pragma unroll
        for (int o = 32; o > 0; o >>= 1) local += __shfl_down(local, o);
        __shared__ float part[4];
        if (lane == 0) part[w] = local;
        __syncthreads();
        if (t == 0) atomicAdd(loss_sum, part[0] + part[1] + part[2] + part[3]);
    }
}

// ---------------------------------------------------------------------------
// Phase-2 sweep: one block per GEMM tile; reads D fragments back in the same
// C-fragment order (coalesced 16B), labels/rns staged in 2KB LDS.
// ---------------------------------------------------------------------------
__global__ __launch_bounds__(256) void pass2_sweep(
    const unsigned short* __restrict__ Dws, const int* __restrict__ labels,
    const float* __restrict__ rns, float* __restrict__ loss_sum)
{
    __shared__ int   lab_i[128], lab_j[128];
    __shared__ float rb_i[128], rb_j[128];

    const int t    = threadIdx.x;
    const int lane = t & 63;
    const int w    = t >> 6;
    const int wi   = w >> 1, wj = w & 1;
    const int bid  = blockIdx.x;
    const int sup  = bid >> 6, loc = bid & 63;
    const int by   = ((sup >> 2) << 3) | (loc >> 3);
    const int bx   = ((sup & 3) << 3) | (loc & 7);
    const int ti   = by * 128;
    const int tj   = bx * 128;
    const int lr   = lane & 15;
    const int lq   = lane >> 4;

    if (t < 128) {
        lab_i[t] = labels[ti + t];
        rb_i[t]  = rns[ti + t];
    } else {
        int u = t - 128;
        lab_j[u] = labels[tj + u];
        rb_j[u]  = rns[tj + u];
    }
    __syncthreads();

    const unsigned short* dblk = Dws + (size_t)bid * 16384;
    float local = 0.f;
    #pragma unroll
    for (int ri = 0; ri < 4; ++ri) {
        short8 d0 = *(const short8*)&dblk[(ri * 2 + 0) * 2048 + t * 8];
        short8 d1 = *(const short8*)&dblk[(ri * 2 + 1) * 2048 + t * 8];
        #pragma unroll
        for (int rj = 0; rj < 4; ++rj) {
            int jl  = wj * 64 + rj * 16 + lr;
            int ljv = lab_j[jl];
            #pragma unroll
            for (int r = 0; r < 4; ++r) {
                int il = wi * 64 + ri * 16 + lq * 4 + r;
                if (lab_i[il] == ljv && (ti + il) != (tj + jl)) {
                    unsigned short du = (rj < 2)
                        ? (unsigned short)d0[rj * 4 + r]
                        : (unsigned short)d1[(rj - 2) * 4 + r];
                    float J = __logf(rb_i[il] + rb_j[jl]) + h2f(du);
                    float h = fmaxf(J, 0.f);
                    local += h * h;
                }
            }
        }
    }
    #pragma unroll
    for (int o = 32; o > 0; o >>= 1) local += __shfl_down(local, o);
    __shared__ float part[4];
    if (lane == 0) part[w] = local;
    __syncthreads();
    if (t == 0) atomicAdd(loss_sum, part[0] + part[1] + part[2] + part[3]);
}

// ---------------------------------------------------------------------------
__global__ __launch_bounds__(256) void finalize_kernel(const int* __restrict__ labels,
                                                       const float* __restrict__ loss_sum,
                                                       float* __restrict__ out) {
    __shared__ int hist[16];
    int t = threadIdx.x;
    if (t < 16) hist[t] = 0;
    __syncthreads();
    for (int i = t; i < NROW; i += 256) atomicAdd(&hist[labels[i] & 15], 1);
    __syncthreads();
    if (t == 0) {
        long long np = 0;
        for (int c = 0; c < 16; ++c) np += (long long)hist[c] * (long long)(hist[c] - 1);
        out[0] = loss_sum[0] / (2.0f * (float)np);
    }
}

// ---------------------------------------------------------------------------
extern "C" void kernel_launch(void* const* d_in, const int* in_sizes, int n_in,
                              void* d_out, int out_size, void* d_ws, size_t ws_size,
                              hipStream_t stream) {
    const float* a      = (const float*)d_in[0];
    const float* b      = (const float*)d_in[1];
    const int*   labels = (const int*)d_in[2];
    float* out = (float*)d_out;

    // ws: abf(8MB) | bbf(8MB) | na,nb,rns,loss(+pad) | Dws(32MB fp16)
    unsigned short* abf = (unsigned short*)d_ws;
    unsigned short* bbf = abf + (size_t)NROW * FDIM;
    float* fws  = (float*)(bbf + (size_t)NROW * FDIM);
    float* na   = fws;
    float* nb   = fws + NROW;
    float* rns  = fws + 2 * NROW;
    float* loss = fws + 3 * NROW;
    unsigned short* Dws = (unsigned short*)(fws + 3 * NROW + 4);   // 16B aligned

    size_t need = ((char*)Dws - (char*)d_ws) + (size_t)NROW * NROW * 2;

    prep_kernel<<<NROW, 64, 0, stream>>>(a, b, abf, bbf, na, nb, rns, loss);

    dim3 grid((NROW / 128) * (NROW / 128));   // 1024 blocks
    if (ws_size >= need) {
        pass_mfma<0><<<grid, 256, 0, stream>>>(abf, bbf, labels, na, nb, rns, Dws, loss);
        pass2_sweep<<<grid, 256, 0, stream>>>(Dws, labels, rns, loss);
    } else {
        pass_mfma<1><<<grid, 256, 0, stream>>>(abf, bbf, labels, na, nb, rns, Dws, loss);
        pass_mfma<2><<<grid, 256, 0, stream>>>(abf, bbf, labels, na, nb, rns, Dws, loss);
    }

    finalize_kernel<<<1, 256, 0, stream>>>(labels, loss, out);
}